// Round 2
// baseline (92.842 us; speedup 1.0000x reference)
//
#include <hip/hip_runtime.h>
#include <math.h>

namespace {

constexpr int Bg   = 2048;   // graphs
constexpr int Nn   = 256;    // nodes per graph
constexpr int Dd   = 128;    // node embed dim
constexpr int Hh   = 4;      // heads
constexpr int SUBn = 32;     // nodes per subset
constexpr int DHd  = 128;    // head embed dim
constexpr int D3   = 384;    // 3*D
constexpr int DH2  = 256;    // 2*DH
constexpr int Gg   = 16;     // graphs per MLP block
constexpr int CSTR = 20;     // LDS stride (float4-aligned, bank-spread)
constexpr float EPSf = 1e-5f;

// ------------------------------------------------------------------
// Kernel 1: gather + segment mean/max/sum  ->  ws combined [B][H][384]
// 1024 blocks x 256 threads; half-wave (32 lanes) per (graph, head)
// ------------------------------------------------------------------
__global__ __launch_bounds__(256, 8)
void gather_k(const float* __restrict__ emb,
              const int* __restrict__ subset,
              const int* __restrict__ batch,
              float* __restrict__ comb_out)
{
    __shared__ int offs[2];
    __shared__ int sn[Hh * SUBn];

    const int t = (int)threadIdx.x;
    if (t < Hh * SUBn) sn[t] = subset[t];
    if (t < 2) {
        const int target = (int)blockIdx.x * 2 + t;
        int lo = 0, hi = Bg * Nn;
        while (lo < hi) {
            const int mid = (lo + hi) >> 1;
            if (batch[mid] < target) lo = mid + 1; else hi = mid;
        }
        offs[t] = lo;
    }
    __syncthreads();

    const int c  = t & 31;        // float4 chunk of D
    const int hw = t >> 5;        // 0..7
    const int gl = hw >> 2;       // 0..1
    const int h  = hw & 3;        // head
    const int b  = (int)blockIdx.x * 2 + gl;
    const size_t off = (size_t)offs[gl];

    float sx = 0.f, sy = 0.f, sz = 0.f, sw = 0.f;
    float mxx = -INFINITY, mxy = -INFINITY, mxz = -INFINITY, mxw = -INFINITY;
    #pragma unroll 8
    for (int s = 0; s < SUBn; ++s) {
        const float4 v = *reinterpret_cast<const float4*>(
            emb + (off + (size_t)sn[h * SUBn + s]) * Dd + c * 4);
        sx += v.x; sy += v.y; sz += v.z; sw += v.w;
        mxx = fmaxf(mxx, v.x); mxy = fmaxf(mxy, v.y);
        mxz = fmaxf(mxz, v.z); mxw = fmaxf(mxw, v.w);
    }

    float* dst = comb_out + ((size_t)b * Hh + h) * D3 + c * 4;
    *reinterpret_cast<float4*>(dst)            = make_float4(sx * 0.03125f, sy * 0.03125f,
                                                             sz * 0.03125f, sw * 0.03125f);
    *reinterpret_cast<float4*>(dst + Dd)       = make_float4(mxx, mxy, mxz, mxw);
    *reinterpret_cast<float4*>(dst + 2 * Dd)   = make_float4(sx, sy, sz, sw);
}

// ------------------------------------------------------------------
// Kernel 2: MLP (proj1+LN+ReLU, proj2+LN+ReLU)
// 512 blocks x 256 threads; block = (head, 16 graphs)
// wave w: j in [w*64, w*64+64); lane = (jg = l&15 -> 4 j, gq = l>>4 -> 4 g)
// each weight element read exactly once per block.
// ------------------------------------------------------------------
__global__ __launch_bounds__(256, 4)
void mlp_k(const float* __restrict__ comb_in,
           const float* __restrict__ w1,
           const float* __restrict__ b1,
           const float* __restrict__ g1,
           const float* __restrict__ be1,
           const float* __restrict__ w2,
           const float* __restrict__ b2,
           const float* __restrict__ g2,
           const float* __restrict__ be2,
           float* __restrict__ out)
{
    __shared__ __align__(16) float comb[D3 * CSTR];   // 30.7 KB, [i][g] stride 20
    __shared__ __align__(16) float h1s[DH2 * CSTR];   // 20.5 KB
    __shared__ __align__(16) float red[2][4][Gg];     // cross-wave LN partials

    const int t = (int)threadIdx.x;

    // XCD-aware mapping: heads 0..3 -> XCD pairs (grid 512 = 8*64, bijective)
    const int bid  = (int)blockIdx.x;
    const int xcd  = bid & 7;
    const int slot = bid >> 3;                 // 0..63
    const int head = xcd >> 1;                 // 0..3
    const int gblk = ((xcd & 1) << 6) + slot;  // 0..127
    const int gbase = gblk * Gg;

    // ---- stage combined[16][384] -> LDS comb[i][g] ----
    {
        const int g  = t & 15;
        const int i4b = (t >> 4) * 6;          // 6 float4 per thread
        const float* src = comb_in + ((size_t)(gbase + g) * Hh + head) * D3;
        #pragma unroll
        for (int k = 0; k < 6; ++k) {
            const int i4 = i4b + k;
            const float4 v = *reinterpret_cast<const float4*>(src + i4 * 4);
            comb[(i4 * 4 + 0) * CSTR + g] = v.x;
            comb[(i4 * 4 + 1) * CSTR + g] = v.y;
            comb[(i4 * 4 + 2) * CSTR + g] = v.z;
            comb[(i4 * 4 + 3) * CSTR + g] = v.w;
        }
    }
    __syncthreads();

    const int lane = t & 63;
    const int wv   = t >> 6;
    const int jg   = lane & 15;
    const int gq   = lane >> 4;
    const int g0   = gq * 4;

    // ---------- proj1 + LN1 + ReLU ----------
    {
        const int j0 = wv * 64 + jg * 4;
        const float* w1h = w1 + (size_t)head * D3 * DH2;

        const float4 bv = *reinterpret_cast<const float4*>(b1 + head * DH2 + j0);
        const float bj[4] = {bv.x, bv.y, bv.z, bv.w};
        float acc[4][4];
        #pragma unroll
        for (int jj = 0; jj < 4; ++jj)
            #pragma unroll
            for (int gg = 0; gg < 4; ++gg)
                acc[jj][gg] = bj[jj];

        #pragma unroll 4
        for (int i = 0; i < D3; ++i) {
            const float4 w4 = *reinterpret_cast<const float4*>(w1h + (size_t)i * DH2 + j0);
            const float4 c4 = *reinterpret_cast<const float4*>(&comb[i * CSTR + g0]);
            const float wj[4] = {w4.x, w4.y, w4.z, w4.w};
            const float cg[4] = {c4.x, c4.y, c4.z, c4.w};
            #pragma unroll
            for (int jj = 0; jj < 4; ++jj)
                #pragma unroll
                for (int gg = 0; gg < 4; ++gg)
                    acc[jj][gg] = fmaf(wj[jj], cg[gg], acc[jj][gg]);
        }

        // partial LN sums over this lane's 4 j, then over the 16-lane j-group
        float s1[4], s2[4];
        #pragma unroll
        for (int gg = 0; gg < 4; ++gg) {
            s1[gg] = acc[0][gg] + acc[1][gg] + acc[2][gg] + acc[3][gg];
            s2[gg] = acc[0][gg] * acc[0][gg] + acc[1][gg] * acc[1][gg]
                   + acc[2][gg] * acc[2][gg] + acc[3][gg] * acc[3][gg];
            #pragma unroll
            for (int m = 1; m < 16; m <<= 1) {
                s1[gg] += __shfl_xor(s1[gg], m, 64);
                s2[gg] += __shfl_xor(s2[gg], m, 64);
            }
        }
        if (jg == 0) {
            #pragma unroll
            for (int gg = 0; gg < 4; ++gg) {
                red[0][wv][g0 + gg] = s1[gg];
                red[1][wv][g0 + gg] = s2[gg];
            }
        }
        __syncthreads();

        float t1[4] = {0.f, 0.f, 0.f, 0.f}, t2[4] = {0.f, 0.f, 0.f, 0.f};
        #pragma unroll
        for (int w = 0; w < 4; ++w) {
            const float4 r1 = *reinterpret_cast<const float4*>(&red[0][w][g0]);
            const float4 r2 = *reinterpret_cast<const float4*>(&red[1][w][g0]);
            t1[0] += r1.x; t1[1] += r1.y; t1[2] += r1.z; t1[3] += r1.w;
            t2[0] += r2.x; t2[1] += r2.y; t2[2] += r2.z; t2[3] += r2.w;
        }

        const float4 gv  = *reinterpret_cast<const float4*>(g1 + j0);
        const float4 bev = *reinterpret_cast<const float4*>(be1 + j0);
        const float gj[4]  = {gv.x, gv.y, gv.z, gv.w};
        const float bej[4] = {bev.x, bev.y, bev.z, bev.w};

        #pragma unroll
        for (int gg = 0; gg < 4; ++gg) {
            const float mean = t1[gg] * (1.f / 256.f);
            const float var  = t2[gg] * (1.f / 256.f) - mean * mean;
            const float rstd = rsqrtf(var + EPSf);
            #pragma unroll
            for (int jj = 0; jj < 4; ++jj)
                h1s[(j0 + jj) * CSTR + (g0 + gg)] =
                    fmaxf(0.f, (acc[jj][gg] - mean) * rstd * gj[jj] + bej[jj]);
        }
    }
    __syncthreads();

    // ---------- proj2 + LN2 + ReLU ----------
    {
        const int j0 = wv * 32 + jg * 2;
        const float* w2h = w2 + (size_t)head * DH2 * DHd;

        const float2 bv = *reinterpret_cast<const float2*>(b2 + head * DHd + j0);
        float acc[2][4];
        #pragma unroll
        for (int gg = 0; gg < 4; ++gg) { acc[0][gg] = bv.x; acc[1][gg] = bv.y; }

        #pragma unroll 4
        for (int i = 0; i < DH2; ++i) {
            const float2 wv2 = *reinterpret_cast<const float2*>(w2h + (size_t)i * DHd + j0);
            const float4 c4  = *reinterpret_cast<const float4*>(&h1s[i * CSTR + g0]);
            const float cg[4] = {c4.x, c4.y, c4.z, c4.w};
            #pragma unroll
            for (int gg = 0; gg < 4; ++gg) {
                acc[0][gg] = fmaf(wv2.x, cg[gg], acc[0][gg]);
                acc[1][gg] = fmaf(wv2.y, cg[gg], acc[1][gg]);
            }
        }

        float s1[4], s2[4];
        #pragma unroll
        for (int gg = 0; gg < 4; ++gg) {
            s1[gg] = acc[0][gg] + acc[1][gg];
            s2[gg] = acc[0][gg] * acc[0][gg] + acc[1][gg] * acc[1][gg];
            #pragma unroll
            for (int m = 1; m < 16; m <<= 1) {
                s1[gg] += __shfl_xor(s1[gg], m, 64);
                s2[gg] += __shfl_xor(s2[gg], m, 64);
            }
        }
        __syncthreads();   // red[] free to reuse (all reads done pre-h1 barrier path)
        if (jg == 0) {
            #pragma unroll
            for (int gg = 0; gg < 4; ++gg) {
                red[0][wv][g0 + gg] = s1[gg];
                red[1][wv][g0 + gg] = s2[gg];
            }
        }
        __syncthreads();

        float t1[4] = {0.f, 0.f, 0.f, 0.f}, t2[4] = {0.f, 0.f, 0.f, 0.f};
        #pragma unroll
        for (int w = 0; w < 4; ++w) {
            const float4 r1 = *reinterpret_cast<const float4*>(&red[0][w][g0]);
            const float4 r2 = *reinterpret_cast<const float4*>(&red[1][w][g0]);
            t1[0] += r1.x; t1[1] += r1.y; t1[2] += r1.z; t1[3] += r1.w;
            t2[0] += r2.x; t2[1] += r2.y; t2[2] += r2.z; t2[3] += r2.w;
        }

        const float2 gv  = *reinterpret_cast<const float2*>(g2 + j0);
        const float2 bev = *reinterpret_cast<const float2*>(be2 + j0);

        #pragma unroll
        for (int gg = 0; gg < 4; ++gg) {
            const float mean = t1[gg] * (1.f / 128.f);
            const float var  = t2[gg] * (1.f / 128.f) - mean * mean;
            const float rstd = rsqrtf(var + EPSf);
            const float o0 = fmaxf(0.f, (acc[0][gg] - mean) * rstd * gv.x + bev.x);
            const float o1 = fmaxf(0.f, (acc[1][gg] - mean) * rstd * gv.y + bev.y);
            const int b = gbase + g0 + gg;
            *reinterpret_cast<float2*>(out + ((size_t)b * Hh + head) * DHd + j0) =
                make_float2(o0, o1);
        }
    }
}

} // namespace

extern "C" void kernel_launch(void* const* d_in, const int* in_sizes, int n_in,
                              void* d_out, int out_size, void* d_ws, size_t ws_size,
                              hipStream_t stream) {
    const float* emb  = (const float*)d_in[0];
    const float* w1   = (const float*)d_in[1];
    const float* b1   = (const float*)d_in[2];
    const float* g1   = (const float*)d_in[3];
    const float* be1  = (const float*)d_in[4];
    const float* w2   = (const float*)d_in[5];
    const float* b2   = (const float*)d_in[6];
    const float* g2   = (const float*)d_in[7];
    const float* be2  = (const float*)d_in[8];
    const int* subset = (const int*)d_in[9];
    const int* batch  = (const int*)d_in[11];
    float* out = (float*)d_out;
    float* comb_ws = (float*)d_ws;   // [B][H][384] f32 = 12.6 MB

    gather_k<<<dim3(Bg / 2), dim3(256), 0, stream>>>(emb, subset, batch, comb_ws);
    mlp_k<<<dim3(Hh * (Bg / Gg)), dim3(256), 0, stream>>>(comb_ws, w1, b1, g1, be1,
                                                          w2, b2, g2, be2, out);
}

// Round 3
// 87.980 us; speedup vs baseline: 1.0553x; 1.0553x over previous
//
#include <hip/hip_runtime.h>
#include <math.h>

namespace {

constexpr int Bg   = 2048;   // graphs
constexpr int Nn   = 256;    // nodes per graph
constexpr int Dd   = 128;    // node embed dim
constexpr int Hh   = 4;      // heads
constexpr int SUBn = 32;     // nodes per subset
constexpr int DHd  = 128;    // head embed dim
constexpr int D3   = 384;    // 3*D
constexpr int DH2  = 256;    // 2*DH
constexpr int Gg   = 16;     // graphs per MLP block
constexpr int CSTR = 20;     // LDS stride (float4-aligned, bank-spread)
constexpr float EPSf = 1e-5f;

// ------------------------------------------------------------------
// Kernel 0: per-graph offsets via parallel binary search over sorted batch
// ------------------------------------------------------------------
__global__ __launch_bounds__(256)
void off_k(const int* __restrict__ batch, int* __restrict__ offs)
{
    const int b = (int)blockIdx.x * 256 + (int)threadIdx.x;
    int lo = 0, hi = Bg * Nn;
    while (lo < hi) {
        const int mid = (lo + hi) >> 1;
        if (batch[mid] < b) lo = mid + 1; else hi = mid;
    }
    offs[b] = lo;
}

// ------------------------------------------------------------------
// Kernel 1: gather + segment mean/max/sum -> ws combined [B][H][384]
// 1 block = 1 graph; wave = head; 16 independent 1KB loads per wave
// (lanes 0-31 -> row 2s, lanes 32-63 -> row 2s+1), combine via shfl_xor(32).
// ------------------------------------------------------------------
__global__ __launch_bounds__(256, 4)
void gather_k(const float* __restrict__ emb,
              const int* __restrict__ subset,
              const int* __restrict__ offs,
              float* __restrict__ comb_out)
{
    __shared__ int sn[Hh * SUBn];
    const int t = (int)threadIdx.x;
    if (t < Hh * SUBn) sn[t] = subset[t];
    __syncthreads();

    const int b    = (int)blockIdx.x;
    const int h    = t >> 6;
    const int lane = t & 63;
    const int half = lane >> 5;
    const int c    = lane & 31;

    const float* base = emb + (size_t)offs[b] * Dd + c * 4;

    float sx = 0.f, sy = 0.f, sz = 0.f, sw = 0.f;
    float mxx = -INFINITY, mxy = -INFINITY, mxz = -INFINITY, mxw = -INFINITY;
    #pragma unroll
    for (int s2 = 0; s2 < 16; ++s2) {
        const int r = sn[h * SUBn + 2 * s2 + half];
        const float4 v = *reinterpret_cast<const float4*>(base + (size_t)r * Dd);
        sx += v.x; sy += v.y; sz += v.z; sw += v.w;
        mxx = fmaxf(mxx, v.x); mxy = fmaxf(mxy, v.y);
        mxz = fmaxf(mxz, v.z); mxw = fmaxf(mxw, v.w);
    }

    // combine the two row-parity halves (lane <-> lane^32)
    sx += __shfl_xor(sx, 32, 64);
    sy += __shfl_xor(sy, 32, 64);
    sz += __shfl_xor(sz, 32, 64);
    sw += __shfl_xor(sw, 32, 64);
    mxx = fmaxf(mxx, __shfl_xor(mxx, 32, 64));
    mxy = fmaxf(mxy, __shfl_xor(mxy, 32, 64));
    mxz = fmaxf(mxz, __shfl_xor(mxz, 32, 64));
    mxw = fmaxf(mxw, __shfl_xor(mxw, 32, 64));

    float* dst = comb_out + ((size_t)b * Hh + h) * D3 + c * 4;
    if (half == 0) {
        *reinterpret_cast<float4*>(dst)      = make_float4(sx * 0.03125f, sy * 0.03125f,
                                                           sz * 0.03125f, sw * 0.03125f);
        *reinterpret_cast<float4*>(dst + Dd) = make_float4(mxx, mxy, mxz, mxw);
    } else {
        *reinterpret_cast<float4*>(dst + 2 * Dd) = make_float4(sx, sy, sz, sw);
    }
}

// ------------------------------------------------------------------
// Kernel 2: MLP (proj1+LN+ReLU, proj2+LN+ReLU)
// 512 blocks x 256 threads; block = (head, 16 graphs)
// each weight element read exactly once per block.
// ------------------------------------------------------------------
__global__ __launch_bounds__(256, 4)
void mlp_k(const float* __restrict__ comb_in,
           const float* __restrict__ w1,
           const float* __restrict__ b1,
           const float* __restrict__ g1,
           const float* __restrict__ be1,
           const float* __restrict__ w2,
           const float* __restrict__ b2,
           const float* __restrict__ g2,
           const float* __restrict__ be2,
           float* __restrict__ out)
{
    __shared__ __align__(16) float comb[D3 * CSTR];   // 30.7 KB, [i][g] stride 20
    __shared__ __align__(16) float h1s[DH2 * CSTR];   // 20.5 KB
    __shared__ __align__(16) float red[2][4][Gg];     // cross-wave LN partials

    const int t = (int)threadIdx.x;

    // XCD-aware mapping: heads 0..3 -> XCD pairs (grid 512 = 8*64, bijective)
    const int bid  = (int)blockIdx.x;
    const int xcd  = bid & 7;
    const int slot = bid >> 3;                 // 0..63
    const int head = xcd >> 1;                 // 0..3
    const int gblk = ((xcd & 1) << 6) + slot;  // 0..127
    const int gbase = gblk * Gg;

    // ---- stage combined[16][384] -> LDS comb[i][g] ----
    {
        const int g  = t & 15;
        const int i4b = (t >> 4) * 6;          // 6 float4 per thread
        const float* src = comb_in + ((size_t)(gbase + g) * Hh + head) * D3;
        #pragma unroll
        for (int k = 0; k < 6; ++k) {
            const int i4 = i4b + k;
            const float4 v = *reinterpret_cast<const float4*>(src + i4 * 4);
            comb[(i4 * 4 + 0) * CSTR + g] = v.x;
            comb[(i4 * 4 + 1) * CSTR + g] = v.y;
            comb[(i4 * 4 + 2) * CSTR + g] = v.z;
            comb[(i4 * 4 + 3) * CSTR + g] = v.w;
        }
    }
    __syncthreads();

    const int lane = t & 63;
    const int wv   = t >> 6;
    const int jg   = lane & 15;
    const int gq   = lane >> 4;
    const int g0   = gq * 4;

    // ---------- proj1 + LN1 + ReLU ----------
    {
        const int j0 = wv * 64 + jg * 4;
        const float* w1h = w1 + (size_t)head * D3 * DH2;

        const float4 bv = *reinterpret_cast<const float4*>(b1 + head * DH2 + j0);
        const float bj[4] = {bv.x, bv.y, bv.z, bv.w};
        float acc[4][4];
        #pragma unroll
        for (int jj = 0; jj < 4; ++jj)
            #pragma unroll
            for (int gg = 0; gg < 4; ++gg)
                acc[jj][gg] = bj[jj];

        #pragma unroll 4
        for (int i = 0; i < D3; ++i) {
            const float4 w4 = *reinterpret_cast<const float4*>(w1h + (size_t)i * DH2 + j0);
            const float4 c4 = *reinterpret_cast<const float4*>(&comb[i * CSTR + g0]);
            const float wj[4] = {w4.x, w4.y, w4.z, w4.w};
            const float cg[4] = {c4.x, c4.y, c4.z, c4.w};
            #pragma unroll
            for (int jj = 0; jj < 4; ++jj)
                #pragma unroll
                for (int gg = 0; gg < 4; ++gg)
                    acc[jj][gg] = fmaf(wj[jj], cg[gg], acc[jj][gg]);
        }

        float s1[4], s2[4];
        #pragma unroll
        for (int gg = 0; gg < 4; ++gg) {
            s1[gg] = acc[0][gg] + acc[1][gg] + acc[2][gg] + acc[3][gg];
            s2[gg] = acc[0][gg] * acc[0][gg] + acc[1][gg] * acc[1][gg]
                   + acc[2][gg] * acc[2][gg] + acc[3][gg] * acc[3][gg];
            #pragma unroll
            for (int m = 1; m < 16; m <<= 1) {
                s1[gg] += __shfl_xor(s1[gg], m, 64);
                s2[gg] += __shfl_xor(s2[gg], m, 64);
            }
        }
        if (jg == 0) {
            #pragma unroll
            for (int gg = 0; gg < 4; ++gg) {
                red[0][wv][g0 + gg] = s1[gg];
                red[1][wv][g0 + gg] = s2[gg];
            }
        }
        __syncthreads();

        float t1[4] = {0.f, 0.f, 0.f, 0.f}, t2[4] = {0.f, 0.f, 0.f, 0.f};
        #pragma unroll
        for (int w = 0; w < 4; ++w) {
            const float4 r1 = *reinterpret_cast<const float4*>(&red[0][w][g0]);
            const float4 r2 = *reinterpret_cast<const float4*>(&red[1][w][g0]);
            t1[0] += r1.x; t1[1] += r1.y; t1[2] += r1.z; t1[3] += r1.w;
            t2[0] += r2.x; t2[1] += r2.y; t2[2] += r2.z; t2[3] += r2.w;
        }

        const float4 gv  = *reinterpret_cast<const float4*>(g1 + j0);
        const float4 bev = *reinterpret_cast<const float4*>(be1 + j0);
        const float gj[4]  = {gv.x, gv.y, gv.z, gv.w};
        const float bej[4] = {bev.x, bev.y, bev.z, bev.w};

        #pragma unroll
        for (int gg = 0; gg < 4; ++gg) {
            const float mean = t1[gg] * (1.f / 256.f);
            const float var  = t2[gg] * (1.f / 256.f) - mean * mean;
            const float rstd = rsqrtf(var + EPSf);
            #pragma unroll
            for (int jj = 0; jj < 4; ++jj)
                h1s[(j0 + jj) * CSTR + (g0 + gg)] =
                    fmaxf(0.f, (acc[jj][gg] - mean) * rstd * gj[jj] + bej[jj]);
        }
    }
    __syncthreads();

    // ---------- proj2 + LN2 + ReLU ----------
    {
        const int j0 = wv * 32 + jg * 2;
        const float* w2h = w2 + (size_t)head * DH2 * DHd;

        const float2 bv = *reinterpret_cast<const float2*>(b2 + head * DHd + j0);
        float acc[2][4];
        #pragma unroll
        for (int gg = 0; gg < 4; ++gg) { acc[0][gg] = bv.x; acc[1][gg] = bv.y; }

        #pragma unroll 4
        for (int i = 0; i < DH2; ++i) {
            const float2 wv2 = *reinterpret_cast<const float2*>(w2h + (size_t)i * DHd + j0);
            const float4 c4  = *reinterpret_cast<const float4*>(&h1s[i * CSTR + g0]);
            const float cg[4] = {c4.x, c4.y, c4.z, c4.w};
            #pragma unroll
            for (int gg = 0; gg < 4; ++gg) {
                acc[0][gg] = fmaf(wv2.x, cg[gg], acc[0][gg]);
                acc[1][gg] = fmaf(wv2.y, cg[gg], acc[1][gg]);
            }
        }

        float s1[4], s2[4];
        #pragma unroll
        for (int gg = 0; gg < 4; ++gg) {
            s1[gg] = acc[0][gg] + acc[1][gg];
            s2[gg] = acc[0][gg] * acc[0][gg] + acc[1][gg] * acc[1][gg];
            #pragma unroll
            for (int m = 1; m < 16; m <<= 1) {
                s1[gg] += __shfl_xor(s1[gg], m, 64);
                s2[gg] += __shfl_xor(s2[gg], m, 64);
            }
        }
        __syncthreads();
        if (jg == 0) {
            #pragma unroll
            for (int gg = 0; gg < 4; ++gg) {
                red[0][wv][g0 + gg] = s1[gg];
                red[1][wv][g0 + gg] = s2[gg];
            }
        }
        __syncthreads();

        float t1[4] = {0.f, 0.f, 0.f, 0.f}, t2[4] = {0.f, 0.f, 0.f, 0.f};
        #pragma unroll
        for (int w = 0; w < 4; ++w) {
            const float4 r1 = *reinterpret_cast<const float4*>(&red[0][w][g0]);
            const float4 r2 = *reinterpret_cast<const float4*>(&red[1][w][g0]);
            t1[0] += r1.x; t1[1] += r1.y; t1[2] += r1.z; t1[3] += r1.w;
            t2[0] += r2.x; t2[1] += r2.y; t2[2] += r2.z; t2[3] += r2.w;
        }

        const float2 gv  = *reinterpret_cast<const float2*>(g2 + j0);
        const float2 bev = *reinterpret_cast<const float2*>(be2 + j0);

        #pragma unroll
        for (int gg = 0; gg < 4; ++gg) {
            const float mean = t1[gg] * (1.f / 128.f);
            const float var  = t2[gg] * (1.f / 128.f) - mean * mean;
            const float rstd = rsqrtf(var + EPSf);
            const float o0 = fmaxf(0.f, (acc[0][gg] - mean) * rstd * gv.x + bev.x);
            const float o1 = fmaxf(0.f, (acc[1][gg] - mean) * rstd * gv.y + bev.y);
            const int b = gbase + g0 + gg;
            *reinterpret_cast<float2*>(out + ((size_t)b * Hh + head) * DHd + j0) =
                make_float2(o0, o1);
        }
    }
}

} // namespace

extern "C" void kernel_launch(void* const* d_in, const int* in_sizes, int n_in,
                              void* d_out, int out_size, void* d_ws, size_t ws_size,
                              hipStream_t stream) {
    const float* emb  = (const float*)d_in[0];
    const float* w1   = (const float*)d_in[1];
    const float* b1   = (const float*)d_in[2];
    const float* g1   = (const float*)d_in[3];
    const float* be1  = (const float*)d_in[4];
    const float* w2   = (const float*)d_in[5];
    const float* b2   = (const float*)d_in[6];
    const float* g2   = (const float*)d_in[7];
    const float* be2  = (const float*)d_in[8];
    const int* subset = (const int*)d_in[9];
    const int* batch  = (const int*)d_in[11];
    float* out = (float*)d_out;

    int*   offs_ws = (int*)d_ws;                              // 2048 ints
    float* comb_ws = (float*)((char*)d_ws + 16384);           // [B][H][384] f32

    off_k   <<<dim3(Bg / 256), dim3(256), 0, stream>>>(batch, offs_ws);
    gather_k<<<dim3(Bg),       dim3(256), 0, stream>>>(emb, subset, offs_ws, comb_ws);
    mlp_k   <<<dim3(Hh * (Bg / Gg)), dim3(256), 0, stream>>>(comb_ws, w1, b1, g1, be1,
                                                             w2, b2, g2, be2, out);
}

// Round 4
// 49.723 us; speedup vs baseline: 1.8672x; 1.7694x over previous
//
#include <hip/hip_runtime.h>
#include <math.h>

namespace {

constexpr int Bg   = 2048;   // graphs
constexpr int Nn   = 256;    // nodes per graph
constexpr int Dd   = 128;    // node embed dim
constexpr int Hh   = 4;      // heads
constexpr int SUBn = 32;     // nodes per subset
constexpr int DHd  = 128;    // head embed dim
constexpr int D3   = 384;    // 3*D
constexpr int DH2  = 256;    // 2*DH
constexpr int Gg   = 16;     // graphs per MLP block
constexpr int XP   = 392;    // X lds row stride (elems): 784 B, 16B-aligned, 2-way bank
constexpr int HP   = 264;    // H1 lds row stride: 528 B, 16B-aligned, 2-way bank
constexpr float EPSf = 1e-5f;

typedef __attribute__((ext_vector_type(8))) short bf16x8;
typedef __attribute__((ext_vector_type(4))) float f32x4;

__device__ __forceinline__ unsigned short bf_rne(float f) {
    union { float f; unsigned int u; } v; v.f = f;
    const unsigned int u = v.u + 0x7FFFu + ((v.u >> 16) & 1u);
    return (unsigned short)(u >> 16);
}

// ------------------------------------------------------------------
// Kernel 0: prep — W1/W2 transpose to bf16 [j][k] + per-graph offsets
// blocks 0..95: w1 tiles; 96..127: w2 tiles; 128..2175: offset scan
// ------------------------------------------------------------------
__global__ __launch_bounds__(256)
void prep_k(const float* __restrict__ w1, const float* __restrict__ w2,
            const int* __restrict__ batch,
            unsigned short* __restrict__ wt1, unsigned short* __restrict__ wt2,
            int* __restrict__ offs)
{
    const int bid = (int)blockIdx.x;
    const int t   = (int)threadIdx.x;

    if (bid >= 128) {
        // boundary scan: offs[v] = first index with batch == v
        const int i = (bid - 128) * 256 + t;
        const int v = batch[i];
        if (i == 0 || batch[i - 1] != v) offs[v] = i;
        return;
    }

    __shared__ float tile[64][65];
    const float* src; unsigned short* dst; int K, J, k0, j0;
    if (bid < 96) {
        const int hb = bid / 24, tl = bid % 24;
        k0 = (tl % 6) * 64; j0 = (tl / 6) * 64;
        K = D3; J = DH2;
        src = w1 + (size_t)hb * D3 * DH2;
        dst = wt1 + (size_t)hb * DH2 * D3;
    } else {
        const int b2 = bid - 96, hb = b2 / 8, tl = b2 % 8;
        k0 = (tl % 4) * 64; j0 = (tl / 4) * 64;
        K = DH2; J = DHd;
        src = w2 + (size_t)hb * DH2 * DHd;
        dst = wt2 + (size_t)hb * DHd * DH2;
    }

    #pragma unroll
    for (int it = 0; it < 16; ++it) {
        const int idx = it * 256 + t;
        tile[idx >> 6][idx & 63] =
            src[(size_t)(k0 + (idx >> 6)) * J + (j0 + (idx & 63))];
    }
    __syncthreads();
    #pragma unroll
    for (int it = 0; it < 16; ++it) {
        const int idx = it * 256 + t;
        const int jr = idx >> 6, kc = idx & 63;
        dst[(size_t)(j0 + jr) * K + (k0 + kc)] = bf_rne(tile[kc][jr]);
    }
}

// ------------------------------------------------------------------
// Kernel 1: gather + segment mean/max/sum -> bf16 combined [B][H][384]
// 1 block = 1 graph; wave = head; 16 independent 1KB loads per wave.
// ------------------------------------------------------------------
__global__ __launch_bounds__(256, 4)
void gather_k(const float* __restrict__ emb,
              const int* __restrict__ subset,
              const int* __restrict__ offs,
              unsigned short* __restrict__ comb)
{
    __shared__ int sn[Hh * SUBn];
    const int t = (int)threadIdx.x;
    if (t < Hh * SUBn) sn[t] = subset[t];
    __syncthreads();

    const int b    = (int)blockIdx.x;
    const int h    = t >> 6;
    const int lane = t & 63;
    const int half = lane >> 5;
    const int c    = lane & 31;

    const float* base = emb + (size_t)offs[b] * Dd + c * 4;

    float sx = 0.f, sy = 0.f, sz = 0.f, sw = 0.f;
    float mxx = -INFINITY, mxy = -INFINITY, mxz = -INFINITY, mxw = -INFINITY;
    #pragma unroll
    for (int s2 = 0; s2 < 16; ++s2) {
        const int r = sn[h * SUBn + 2 * s2 + half];
        const float4 v = *reinterpret_cast<const float4*>(base + (size_t)r * Dd);
        sx += v.x; sy += v.y; sz += v.z; sw += v.w;
        mxx = fmaxf(mxx, v.x); mxy = fmaxf(mxy, v.y);
        mxz = fmaxf(mxz, v.z); mxw = fmaxf(mxw, v.w);
    }

    sx += __shfl_xor(sx, 32, 64);
    sy += __shfl_xor(sy, 32, 64);
    sz += __shfl_xor(sz, 32, 64);
    sw += __shfl_xor(sw, 32, 64);
    mxx = fmaxf(mxx, __shfl_xor(mxx, 32, 64));
    mxy = fmaxf(mxy, __shfl_xor(mxy, 32, 64));
    mxz = fmaxf(mxz, __shfl_xor(mxz, 32, 64));
    mxw = fmaxf(mxw, __shfl_xor(mxw, 32, 64));

    unsigned short* dst = comb + ((size_t)b * Hh + h) * D3 + c * 4;
    if (half == 0) {
        *reinterpret_cast<ushort4*>(dst) =
            make_ushort4(bf_rne(sx * 0.03125f), bf_rne(sy * 0.03125f),
                         bf_rne(sz * 0.03125f), bf_rne(sw * 0.03125f));
        *reinterpret_cast<ushort4*>(dst + Dd) =
            make_ushort4(bf_rne(mxx), bf_rne(mxy), bf_rne(mxz), bf_rne(mxw));
    } else {
        *reinterpret_cast<ushort4*>(dst + 2 * Dd) =
            make_ushort4(bf_rne(sx), bf_rne(sy), bf_rne(sz), bf_rne(sw));
    }
}

// ------------------------------------------------------------------
// Kernel 2: MFMA MLP. block = (head, 16 graphs), 512 blocks x 256 thr.
// mfma_f32_16x16x32_bf16: A = X[16g x K] (LDS), B = Wt[K x 16j] (global,
// j-major k-contiguous). D: col(lane&15)=j, row((lane>>4)*4+reg)=graph.
// ------------------------------------------------------------------
__global__ __launch_bounds__(256, 2)
void mlp_k(const unsigned short* __restrict__ comb,
           const unsigned short* __restrict__ wt1,
           const unsigned short* __restrict__ wt2,
           const float* __restrict__ b1, const float* __restrict__ g1,
           const float* __restrict__ be1,
           const float* __restrict__ b2, const float* __restrict__ g2,
           const float* __restrict__ be2,
           float* __restrict__ out)
{
    __shared__ __align__(16) unsigned short X[Gg * XP];
    __shared__ __align__(16) unsigned short H1s[Gg * HP];
    __shared__ float red[2][4][Gg];

    const int t   = (int)threadIdx.x;
    const int bid = (int)blockIdx.x;
    const int xcd = bid & 7, slot = bid >> 3;
    const int head = xcd >> 1;
    const int gblk = ((xcd & 1) << 6) + slot;
    const int gbase = gblk * Gg;

    // stage combined[16 g][384] bf16 -> LDS (padded rows)
    {
        const int g = t >> 4, i = t & 15;
        const uint4* s4 = reinterpret_cast<const uint4*>(
            comb + ((size_t)(gbase + g) * Hh + head) * D3 + i * 24);
        uint4* d4 = reinterpret_cast<uint4*>(X + g * XP + i * 24);
        d4[0] = s4[0]; d4[1] = s4[1]; d4[2] = s4[2];
    }
    __syncthreads();

    const int lane = t & 63, wv = t >> 6;
    const int lrow = lane & 15, q = lane >> 4;

    // ---------- proj1: [16 x 384] x [384 x 256] ----------
    bf16x8 a1[12];
    #pragma unroll
    for (int k0 = 0; k0 < 12; ++k0)
        a1[k0] = *reinterpret_cast<const bf16x8*>(X + lrow * XP + k0 * 32 + q * 8);

    f32x4 acc[4];
    #pragma unroll
    for (int jt = 0; jt < 4; ++jt) {
        const int j = wv * 64 + jt * 16 + lrow;
        const float bj = b1[head * DH2 + j];
        f32x4 c = {bj, bj, bj, bj};
        const unsigned short* wp = wt1 + ((size_t)head * DH2 + j) * D3 + q * 8;
        #pragma unroll
        for (int k0 = 0; k0 < 12; ++k0)
            c = __builtin_amdgcn_mfma_f32_16x16x32_bf16(
                    a1[k0], *reinterpret_cast<const bf16x8*>(wp + k0 * 32), c, 0, 0, 0);
        acc[jt] = c;
    }

    // ---------- LN1 + ReLU -> H1 (bf16 LDS) ----------
    {
        float s1[4], s2[4];
        #pragma unroll
        for (int r = 0; r < 4; ++r) {
            float a = acc[0][r] + acc[1][r] + acc[2][r] + acc[3][r];
            float b = acc[0][r] * acc[0][r] + acc[1][r] * acc[1][r]
                    + acc[2][r] * acc[2][r] + acc[3][r] * acc[3][r];
            #pragma unroll
            for (int m = 1; m < 16; m <<= 1) {
                a += __shfl_xor(a, m, 64);
                b += __shfl_xor(b, m, 64);
            }
            s1[r] = a; s2[r] = b;
        }
        if (lrow == 0) {
            #pragma unroll
            for (int r = 0; r < 4; ++r) {
                red[0][wv][q * 4 + r] = s1[r];
                red[1][wv][q * 4 + r] = s2[r];
            }
        }
        __syncthreads();

        float t1[4] = {0.f, 0.f, 0.f, 0.f}, t2[4] = {0.f, 0.f, 0.f, 0.f};
        #pragma unroll
        for (int w = 0; w < 4; ++w) {
            const float4 r1 = *reinterpret_cast<const float4*>(&red[0][w][q * 4]);
            const float4 r2 = *reinterpret_cast<const float4*>(&red[1][w][q * 4]);
            t1[0] += r1.x; t1[1] += r1.y; t1[2] += r1.z; t1[3] += r1.w;
            t2[0] += r2.x; t2[1] += r2.y; t2[2] += r2.z; t2[3] += r2.w;
        }
        float mean[4], rstd[4];
        #pragma unroll
        for (int r = 0; r < 4; ++r) {
            mean[r] = t1[r] * (1.f / 256.f);
            const float var = t2[r] * (1.f / 256.f) - mean[r] * mean[r];
            rstd[r] = rsqrtf(var + EPSf);
        }
        #pragma unroll
        for (int jt = 0; jt < 4; ++jt) {
            const int j = wv * 64 + jt * 16 + lrow;
            const float gj = g1[j], bj = be1[j];
            #pragma unroll
            for (int r = 0; r < 4; ++r) {
                const float h = fmaxf(0.f, (acc[jt][r] - mean[r]) * rstd[r] * gj + bj);
                H1s[(q * 4 + r) * HP + j] = bf_rne(h);
            }
        }
    }
    __syncthreads();

    // ---------- proj2: [16 x 256] x [256 x 128] ----------
    bf16x8 a2[8];
    #pragma unroll
    for (int k0 = 0; k0 < 8; ++k0)
        a2[k0] = *reinterpret_cast<const bf16x8*>(H1s + lrow * HP + k0 * 32 + q * 8);

    f32x4 acc2[2];
    #pragma unroll
    for (int jt = 0; jt < 2; ++jt) {
        const int j = wv * 32 + jt * 16 + lrow;
        const float bj = b2[head * DHd + j];
        f32x4 c = {bj, bj, bj, bj};
        const unsigned short* wp = wt2 + ((size_t)head * DHd + j) * DH2 + q * 8;
        #pragma unroll
        for (int k0 = 0; k0 < 8; ++k0)
            c = __builtin_amdgcn_mfma_f32_16x16x32_bf16(
                    a2[k0], *reinterpret_cast<const bf16x8*>(wp + k0 * 32), c, 0, 0, 0);
        acc2[jt] = c;
    }

    // ---------- LN2 + ReLU -> out ----------
    {
        float s1[4], s2[4];
        #pragma unroll
        for (int r = 0; r < 4; ++r) {
            float a = acc2[0][r] + acc2[1][r];
            float b = acc2[0][r] * acc2[0][r] + acc2[1][r] * acc2[1][r];
            #pragma unroll
            for (int m = 1; m < 16; m <<= 1) {
                a += __shfl_xor(a, m, 64);
                b += __shfl_xor(b, m, 64);
            }
            s1[r] = a; s2[r] = b;
        }
        __syncthreads();   // all LN1-era red reads are long done; reuse red
        if (lrow == 0) {
            #pragma unroll
            for (int r = 0; r < 4; ++r) {
                red[0][wv][q * 4 + r] = s1[r];
                red[1][wv][q * 4 + r] = s2[r];
            }
        }
        __syncthreads();

        float t1[4] = {0.f, 0.f, 0.f, 0.f}, t2[4] = {0.f, 0.f, 0.f, 0.f};
        #pragma unroll
        for (int w = 0; w < 4; ++w) {
            const float4 r1 = *reinterpret_cast<const float4*>(&red[0][w][q * 4]);
            const float4 r2 = *reinterpret_cast<const float4*>(&red[1][w][q * 4]);
            t1[0] += r1.x; t1[1] += r1.y; t1[2] += r1.z; t1[3] += r1.w;
            t2[0] += r2.x; t2[1] += r2.y; t2[2] += r2.z; t2[3] += r2.w;
        }
        #pragma unroll
        for (int r = 0; r < 4; ++r) {
            const float mean = t1[r] * (1.f / 128.f);
            const float var  = t2[r] * (1.f / 128.f) - mean * mean;
            const float rstd = rsqrtf(var + EPSf);
            #pragma unroll
            for (int jt = 0; jt < 2; ++jt) {
                const int j = wv * 32 + jt * 16 + lrow;
                const float o = fmaxf(0.f,
                    (acc2[jt][r] - mean) * rstd * g2[j] + be2[j]);
                out[(size_t)(gbase + q * 4 + r) * (Hh * DHd) + head * DHd + j] = o;
            }
        }
    }
}

} // namespace

extern "C" void kernel_launch(void* const* d_in, const int* in_sizes, int n_in,
                              void* d_out, int out_size, void* d_ws, size_t ws_size,
                              hipStream_t stream) {
    const float* emb  = (const float*)d_in[0];
    const float* w1   = (const float*)d_in[1];
    const float* b1   = (const float*)d_in[2];
    const float* g1   = (const float*)d_in[3];
    const float* be1  = (const float*)d_in[4];
    const float* w2   = (const float*)d_in[5];
    const float* b2   = (const float*)d_in[6];
    const float* g2   = (const float*)d_in[7];
    const float* be2  = (const float*)d_in[8];
    const int* subset = (const int*)d_in[9];
    const int* batch  = (const int*)d_in[11];
    float* out = (float*)d_out;

    int* offs = (int*)d_ws;                                            // 8 KB
    unsigned short* wt1 = (unsigned short*)((char*)d_ws + 16384);      // 4*256*384 bf16
    unsigned short* wt2 = wt1 + (size_t)Hh * DH2 * D3;                 // 4*128*256 bf16
    unsigned short* comb = wt2 + (size_t)Hh * DHd * DH2;               // B*H*384 bf16

    prep_k  <<<dim3(128 + Bg * Nn / 256), dim3(256), 0, stream>>>(w1, w2, batch,
                                                                  wt1, wt2, offs);
    gather_k<<<dim3(Bg), dim3(256), 0, stream>>>(emb, subset, offs, comb);
    mlp_k   <<<dim3(Hh * (Bg / Gg)), dim3(256), 0, stream>>>(comb, wt1, wt2,
                                                             b1, g1, be1,
                                                             b2, g2, be2, out);
}

// Round 5
// 46.053 us; speedup vs baseline: 2.0160x; 1.0797x over previous
//
#include <hip/hip_runtime.h>
#include <math.h>

namespace {

constexpr int Bg   = 2048;   // graphs
constexpr int Nn   = 256;    // nodes per graph
constexpr int Dd   = 128;    // node embed dim
constexpr int Hh   = 4;      // heads
constexpr int SUBn = 32;     // nodes per subset
constexpr int DHd  = 128;    // head embed dim
constexpr int D3   = 384;    // 3*D
constexpr int DH2  = 256;    // 2*DH
constexpr int Gg   = 16;     // graphs per block
constexpr int XP   = 392;    // X lds row stride (bf16 elems): 784 B -> 2-way banks
constexpr int HP   = 264;    // H1 lds row stride: 528 B -> 2-way banks
constexpr float EPSf = 1e-5f;

typedef __attribute__((ext_vector_type(8))) short bf16x8;
typedef __attribute__((ext_vector_type(4))) float f32x4;

__device__ __forceinline__ unsigned short bf_rne(float f) {
    union { float f; unsigned int u; } v; v.f = f;
    const unsigned int u = v.u + 0x7FFFu + ((v.u >> 16) & 1u);
    return (unsigned short)(u >> 16);
}

// ------------------------------------------------------------------
// Kernel 0: prep — W1/W2 transpose to bf16 [j][k] + per-graph offsets
// blocks 0..95: w1 tiles; 96..127: w2 tiles; 128..2175: offset scan
// ------------------------------------------------------------------
__global__ __launch_bounds__(256)
void prep_k(const float* __restrict__ w1, const float* __restrict__ w2,
            const int* __restrict__ batch,
            unsigned short* __restrict__ wt1, unsigned short* __restrict__ wt2,
            int* __restrict__ offs)
{
    const int bid = (int)blockIdx.x;
    const int t   = (int)threadIdx.x;

    if (bid >= 128) {
        const int i = (bid - 128) * 256 + t;
        const int v = batch[i];
        if (i == 0 || batch[i - 1] != v) offs[v] = i;
        return;
    }

    __shared__ float tile[64][65];
    const float* src; unsigned short* dst; int K, J, k0, j0;
    if (bid < 96) {
        const int hb = bid / 24, tl = bid % 24;
        k0 = (tl % 6) * 64; j0 = (tl / 6) * 64;
        K = D3; J = DH2;
        src = w1 + (size_t)hb * D3 * DH2;
        dst = wt1 + (size_t)hb * DH2 * D3;
    } else {
        const int b2 = bid - 96, hb = b2 / 8, tl = b2 % 8;
        k0 = (tl % 4) * 64; j0 = (tl / 4) * 64;
        K = DH2; J = DHd;
        src = w2 + (size_t)hb * DH2 * DHd;
        dst = wt2 + (size_t)hb * DHd * DH2;
    }

    #pragma unroll
    for (int it = 0; it < 16; ++it) {
        const int idx = it * 256 + t;
        tile[idx >> 6][idx & 63] =
            src[(size_t)(k0 + (idx >> 6)) * J + (j0 + (idx & 63))];
    }
    __syncthreads();
    #pragma unroll
    for (int it = 0; it < 16; ++it) {
        const int idx = it * 256 + t;
        const int jr = idx >> 6, kc = idx & 63;
        dst[(size_t)(j0 + jr) * K + (k0 + kc)] = bf_rne(tile[kc][jr]);
    }
}

// ------------------------------------------------------------------
// Kernel 1: FUSED gather+reduce+MLP. block = (head, 16 graphs), 512 blocks.
// Phase A: stream 16 x 16KB contiguous extents, reduce mean/max/sum in regs,
//          write bf16 X tile to LDS (combined never hits global).
// Phase B: mfma_f32_16x16x32_bf16 MLP, LN via shfl + tiny LDS reduce
//          (identical to validated round-4 mlp_k).
// ------------------------------------------------------------------
__global__ __launch_bounds__(256, 4)
void fused_k(const float* __restrict__ emb,
             const unsigned short* __restrict__ wt1,
             const unsigned short* __restrict__ wt2,
             const int* __restrict__ subset,
             const int* __restrict__ offs,
             const float* __restrict__ b1, const float* __restrict__ g1,
             const float* __restrict__ be1,
             const float* __restrict__ b2, const float* __restrict__ g2,
             const float* __restrict__ be2,
             float* __restrict__ out)
{
    __shared__ __align__(16) unsigned short X[Gg * XP];    // 12.5 KB
    __shared__ __align__(16) unsigned short H1s[Gg * HP];  // 8.4 KB
    __shared__ float red[2][4][Gg];
    __shared__ int sn[SUBn];
    __shared__ int soff[Gg];

    const int t   = (int)threadIdx.x;
    const int bid = (int)blockIdx.x;
    const int xcd = bid & 7, slot = bid >> 3;
    const int head = xcd >> 1;
    const int gblk = ((xcd & 1) << 6) + slot;
    const int gbase = gblk * Gg;

    if (t < SUBn) sn[t] = subset[head * SUBn + t];
    if (t >= 64 && t < 64 + Gg) soff[t - 64] = offs[gbase + (t - 64)];
    __syncthreads();

    // ---------- Phase A: gather + mean/max/sum -> X (bf16 LDS) ----------
    {
        const int g  = t >> 4;       // graph 0..15
        const int cp = t & 15;       // chunk pair: chunks cp and cp+16
        const float* base = emb + (size_t)soff[g] * Dd;

        float sAx = 0.f, sAy = 0.f, sAz = 0.f, sAw = 0.f;
        float sBx = 0.f, sBy = 0.f, sBz = 0.f, sBw = 0.f;
        float mAx = -INFINITY, mAy = -INFINITY, mAz = -INFINITY, mAw = -INFINITY;
        float mBx = -INFINITY, mBy = -INFINITY, mBz = -INFINITY, mBw = -INFINITY;

        #pragma unroll 4
        for (int s = 0; s < SUBn; ++s) {
            const float* rp = base + (size_t)sn[s] * Dd;
            const float4 va = *reinterpret_cast<const float4*>(rp + cp * 4);
            const float4 vb = *reinterpret_cast<const float4*>(rp + cp * 4 + 64);
            sAx += va.x; sAy += va.y; sAz += va.z; sAw += va.w;
            sBx += vb.x; sBy += vb.y; sBz += vb.z; sBw += vb.w;
            mAx = fmaxf(mAx, va.x); mAy = fmaxf(mAy, va.y);
            mAz = fmaxf(mAz, va.z); mAw = fmaxf(mAw, va.w);
            mBx = fmaxf(mBx, vb.x); mBy = fmaxf(mBy, vb.y);
            mBz = fmaxf(mBz, vb.z); mBw = fmaxf(mBw, vb.w);
        }

        unsigned short* xr = X + g * XP;
        const int dA = cp * 4, dB = cp * 4 + 64;
        *reinterpret_cast<ushort4*>(xr + dA) =
            make_ushort4(bf_rne(sAx * 0.03125f), bf_rne(sAy * 0.03125f),
                         bf_rne(sAz * 0.03125f), bf_rne(sAw * 0.03125f));
        *reinterpret_cast<ushort4*>(xr + dB) =
            make_ushort4(bf_rne(sBx * 0.03125f), bf_rne(sBy * 0.03125f),
                         bf_rne(sBz * 0.03125f), bf_rne(sBw * 0.03125f));
        *reinterpret_cast<ushort4*>(xr + Dd + dA) =
            make_ushort4(bf_rne(mAx), bf_rne(mAy), bf_rne(mAz), bf_rne(mAw));
        *reinterpret_cast<ushort4*>(xr + Dd + dB) =
            make_ushort4(bf_rne(mBx), bf_rne(mBy), bf_rne(mBz), bf_rne(mBw));
        *reinterpret_cast<ushort4*>(xr + 2 * Dd + dA) =
            make_ushort4(bf_rne(sAx), bf_rne(sAy), bf_rne(sAz), bf_rne(sAw));
        *reinterpret_cast<ushort4*>(xr + 2 * Dd + dB) =
            make_ushort4(bf_rne(sBx), bf_rne(sBy), bf_rne(sBz), bf_rne(sBw));
    }
    __syncthreads();

    const int lane = t & 63, wv = t >> 6;
    const int lrow = lane & 15, q = lane >> 4;

    // ---------- proj1: [16 x 384] x [384 x 256] ----------
    bf16x8 a1[12];
    #pragma unroll
    for (int k0 = 0; k0 < 12; ++k0)
        a1[k0] = *reinterpret_cast<const bf16x8*>(X + lrow * XP + k0 * 32 + q * 8);

    f32x4 acc[4];
    #pragma unroll
    for (int jt = 0; jt < 4; ++jt) {
        const int j = wv * 64 + jt * 16 + lrow;
        const float bj = b1[head * DH2 + j];
        f32x4 c = {bj, bj, bj, bj};
        const unsigned short* wp = wt1 + ((size_t)head * DH2 + j) * D3 + q * 8;
        #pragma unroll
        for (int k0 = 0; k0 < 12; ++k0)
            c = __builtin_amdgcn_mfma_f32_16x16x32_bf16(
                    a1[k0], *reinterpret_cast<const bf16x8*>(wp + k0 * 32), c, 0, 0, 0);
        acc[jt] = c;
    }

    // ---------- LN1 + ReLU -> H1 (bf16 LDS) ----------
    {
        float s1[4], s2[4];
        #pragma unroll
        for (int r = 0; r < 4; ++r) {
            float a = acc[0][r] + acc[1][r] + acc[2][r] + acc[3][r];
            float b = acc[0][r] * acc[0][r] + acc[1][r] * acc[1][r]
                    + acc[2][r] * acc[2][r] + acc[3][r] * acc[3][r];
            #pragma unroll
            for (int m = 1; m < 16; m <<= 1) {
                a += __shfl_xor(a, m, 64);
                b += __shfl_xor(b, m, 64);
            }
            s1[r] = a; s2[r] = b;
        }
        if (lrow == 0) {
            #pragma unroll
            for (int r = 0; r < 4; ++r) {
                red[0][wv][q * 4 + r] = s1[r];
                red[1][wv][q * 4 + r] = s2[r];
            }
        }
        __syncthreads();

        float t1[4] = {0.f, 0.f, 0.f, 0.f}, t2[4] = {0.f, 0.f, 0.f, 0.f};
        #pragma unroll
        for (int w = 0; w < 4; ++w) {
            const float4 r1 = *reinterpret_cast<const float4*>(&red[0][w][q * 4]);
            const float4 r2 = *reinterpret_cast<const float4*>(&red[1][w][q * 4]);
            t1[0] += r1.x; t1[1] += r1.y; t1[2] += r1.z; t1[3] += r1.w;
            t2[0] += r2.x; t2[1] += r2.y; t2[2] += r2.z; t2[3] += r2.w;
        }
        float mean[4], rstd[4];
        #pragma unroll
        for (int r = 0; r < 4; ++r) {
            mean[r] = t1[r] * (1.f / 256.f);
            const float var = t2[r] * (1.f / 256.f) - mean[r] * mean[r];
            rstd[r] = rsqrtf(var + EPSf);
        }
        #pragma unroll
        for (int jt = 0; jt < 4; ++jt) {
            const int j = wv * 64 + jt * 16 + lrow;
            const float gj = g1[j], bj = be1[j];
            #pragma unroll
            for (int r = 0; r < 4; ++r) {
                const float h = fmaxf(0.f, (acc[jt][r] - mean[r]) * rstd[r] * gj + bj);
                H1s[(q * 4 + r) * HP + j] = bf_rne(h);
            }
        }
    }
    __syncthreads();

    // ---------- proj2: [16 x 256] x [256 x 128] ----------
    bf16x8 a2[8];
    #pragma unroll
    for (int k0 = 0; k0 < 8; ++k0)
        a2[k0] = *reinterpret_cast<const bf16x8*>(H1s + lrow * HP + k0 * 32 + q * 8);

    f32x4 acc2[2];
    #pragma unroll
    for (int jt = 0; jt < 2; ++jt) {
        const int j = wv * 32 + jt * 16 + lrow;
        const float bj = b2[head * DHd + j];
        f32x4 c = {bj, bj, bj, bj};
        const unsigned short* wp = wt2 + ((size_t)head * DHd + j) * DH2 + q * 8;
        #pragma unroll
        for (int k0 = 0; k0 < 8; ++k0)
            c = __builtin_amdgcn_mfma_f32_16x16x32_bf16(
                    a2[k0], *reinterpret_cast<const bf16x8*>(wp + k0 * 32), c, 0, 0, 0);
        acc2[jt] = c;
    }

    // ---------- LN2 + ReLU -> out ----------
    {
        float s1[4], s2[4];
        #pragma unroll
        for (int r = 0; r < 4; ++r) {
            float a = acc2[0][r] + acc2[1][r];
            float b = acc2[0][r] * acc2[0][r] + acc2[1][r] * acc2[1][r];
            #pragma unroll
            for (int m = 1; m < 16; m <<= 1) {
                a += __shfl_xor(a, m, 64);
                b += __shfl_xor(b, m, 64);
            }
            s1[r] = a; s2[r] = b;
        }
        __syncthreads();
        if (lrow == 0) {
            #pragma unroll
            for (int r = 0; r < 4; ++r) {
                red[0][wv][q * 4 + r] = s1[r];
                red[1][wv][q * 4 + r] = s2[r];
            }
        }
        __syncthreads();

        float t1[4] = {0.f, 0.f, 0.f, 0.f}, t2[4] = {0.f, 0.f, 0.f, 0.f};
        #pragma unroll
        for (int w = 0; w < 4; ++w) {
            const float4 r1 = *reinterpret_cast<const float4*>(&red[0][w][q * 4]);
            const float4 r2 = *reinterpret_cast<const float4*>(&red[1][w][q * 4]);
            t1[0] += r1.x; t1[1] += r1.y; t1[2] += r1.z; t1[3] += r1.w;
            t2[0] += r2.x; t2[1] += r2.y; t2[2] += r2.z; t2[3] += r2.w;
        }
        #pragma unroll
        for (int r = 0; r < 4; ++r) {
            const float mean = t1[r] * (1.f / 128.f);
            const float var  = t2[r] * (1.f / 128.f) - mean * mean;
            const float rstd = rsqrtf(var + EPSf);
            #pragma unroll
            for (int jt = 0; jt < 2; ++jt) {
                const int j = wv * 32 + jt * 16 + lrow;
                const float o = fmaxf(0.f,
                    (acc2[jt][r] - mean) * rstd * g2[j] + be2[j]);
                out[(size_t)(gbase + q * 4 + r) * (Hh * DHd) + head * DHd + j] = o;
            }
        }
    }
}

} // namespace

extern "C" void kernel_launch(void* const* d_in, const int* in_sizes, int n_in,
                              void* d_out, int out_size, void* d_ws, size_t ws_size,
                              hipStream_t stream) {
    const float* emb  = (const float*)d_in[0];
    const float* w1   = (const float*)d_in[1];
    const float* b1   = (const float*)d_in[2];
    const float* g1   = (const float*)d_in[3];
    const float* be1  = (const float*)d_in[4];
    const float* w2   = (const float*)d_in[5];
    const float* b2   = (const float*)d_in[6];
    const float* g2   = (const float*)d_in[7];
    const float* be2  = (const float*)d_in[8];
    const int* subset = (const int*)d_in[9];
    const int* batch  = (const int*)d_in[11];
    float* out = (float*)d_out;

    int* offs = (int*)d_ws;                                            // 8 KB
    unsigned short* wt1 = (unsigned short*)((char*)d_ws + 16384);      // 4*256*384 bf16
    unsigned short* wt2 = wt1 + (size_t)Hh * DH2 * D3;                 // 4*128*256 bf16

    prep_k <<<dim3(128 + Bg * Nn / 256), dim3(256), 0, stream>>>(w1, w2, batch,
                                                                 wt1, wt2, offs);
    fused_k<<<dim3(Hh * (Bg / Gg)), dim3(256), 0, stream>>>(emb, wt1, wt2,
                                                            subset, offs,
                                                            b1, g1, be1,
                                                            b2, g2, be2, out);
}